// Round 6
// baseline (164.076 us; speedup 1.0000x reference)
//
#include <hip/hip_runtime.h>
#include <math.h>

// WL1 loss over [B=16, C=3, H=512, W=512] fp32.
//   r = sum_c|hr-sr|/255 ; e = sum_c|hr-ema|/255
//   patch_w[b] = (unbiased var of r over sample)^0.2
//   pixel_w = unbiased 3x3 local var of r (reflect pad)
//   loss = mean(|w*sr - w*hr|) = (1/N) sum patch_w * pixel_w * mask * 255*r
//
// R7: structure decomposition. Evidence R1-R6: every stencil-structured
// kernel (LDS tile or rolling regs; occ 16-64%) plateaus at ~2.5 TB/s while
// a plain float4 streaming copy hits 6.3 TB/s on this chip. So: split into
//  K1 wl1_stream — copy-shaped flat pass: 18 coalesced float4 loads/thread,
//     computes r,e; writes sign-encoded m=(r>=e)?r:-r to a 16.8MB ws field;
//     v1/v2 partials. No LDS tile, no barriers in hot path, no branches.
//  K2 wl1_var — R6's LDS-tile stencil on the 9x-smaller m-field (L2/L3
//     resident): 3x3 unbiased var, mask from sign bit, v3 partials.
//  K3 wl1_final — double-precision final reduce (unchanged math).

#define BB 16
#define HH 512
#define WW 512
#define HW (HH * WW)
#define CHW (3 * HW)

// ---- K1 geometry: 2048 blocks x 256 thr, 8 px/thread (2 float4 quads) ----
#define NB1 2048
// ---- K2 geometry: tile 8x256, 2048 blocks ----
#define NB2 2048
#define LDS_STRIDE 264  // col 3 = left halo, 4..259 = centers, 260 = right halo

__device__ __forceinline__ int reflect_h(int gh) {
  gh = gh < 0 ? -gh : gh;
  return gh >= HH ? 2 * HH - 2 - gh : gh;
}

__global__ __launch_bounds__(256) void wl1_stream(
    const float* __restrict__ sr, const float* __restrict__ srema,
    const float* __restrict__ hr, float* __restrict__ rfield,
    float* __restrict__ p_sum, float* __restrict__ p_sum2) {
  const int tid = threadIdx.x;
  const int bid = blockIdx.x;
  const int b = bid >> 7;                          // 128 blocks per batch
  const int rem = ((bid & 127) << 9) + (tid << 1); // quad index within batch
  const size_t base = (size_t)b * CHW + ((size_t)rem << 2);
  const float* __restrict__ hp = hr + base;
  const float* __restrict__ sp = sr + base;
  const float* __restrict__ ep = srema + base;

  // 18 independent coalesced float4 loads (lane: 32B contiguous per stream)
  float4 h0a = *(const float4*)(hp);
  float4 h0b = *(const float4*)(hp + 4);
  float4 h1a = *(const float4*)(hp + HW);
  float4 h1b = *(const float4*)(hp + HW + 4);
  float4 h2a = *(const float4*)(hp + 2 * HW);
  float4 h2b = *(const float4*)(hp + 2 * HW + 4);
  float4 s0a = *(const float4*)(sp);
  float4 s0b = *(const float4*)(sp + 4);
  float4 s1a = *(const float4*)(sp + HW);
  float4 s1b = *(const float4*)(sp + HW + 4);
  float4 s2a = *(const float4*)(sp + 2 * HW);
  float4 s2b = *(const float4*)(sp + 2 * HW + 4);
  float4 e0a = *(const float4*)(ep);
  float4 e0b = *(const float4*)(ep + 4);
  float4 e1a = *(const float4*)(ep + HW);
  float4 e1b = *(const float4*)(ep + HW + 4);
  float4 e2a = *(const float4*)(ep + 2 * HW);
  float4 e2b = *(const float4*)(ep + 2 * HW + 4);

  float4 ra, rb, ea, eb2;
  ra.x = (fabsf(h0a.x - s0a.x) + fabsf(h1a.x - s1a.x) + fabsf(h2a.x - s2a.x)) / 255.0f;
  ra.y = (fabsf(h0a.y - s0a.y) + fabsf(h1a.y - s1a.y) + fabsf(h2a.y - s2a.y)) / 255.0f;
  ra.z = (fabsf(h0a.z - s0a.z) + fabsf(h1a.z - s1a.z) + fabsf(h2a.z - s2a.z)) / 255.0f;
  ra.w = (fabsf(h0a.w - s0a.w) + fabsf(h1a.w - s1a.w) + fabsf(h2a.w - s2a.w)) / 255.0f;
  rb.x = (fabsf(h0b.x - s0b.x) + fabsf(h1b.x - s1b.x) + fabsf(h2b.x - s2b.x)) / 255.0f;
  rb.y = (fabsf(h0b.y - s0b.y) + fabsf(h1b.y - s1b.y) + fabsf(h2b.y - s2b.y)) / 255.0f;
  rb.z = (fabsf(h0b.z - s0b.z) + fabsf(h1b.z - s1b.z) + fabsf(h2b.z - s2b.z)) / 255.0f;
  rb.w = (fabsf(h0b.w - s0b.w) + fabsf(h1b.w - s1b.w) + fabsf(h2b.w - s2b.w)) / 255.0f;
  ea.x = (fabsf(h0a.x - e0a.x) + fabsf(h1a.x - e1a.x) + fabsf(h2a.x - e2a.x)) / 255.0f;
  ea.y = (fabsf(h0a.y - e0a.y) + fabsf(h1a.y - e1a.y) + fabsf(h2a.y - e2a.y)) / 255.0f;
  ea.z = (fabsf(h0a.z - e0a.z) + fabsf(h1a.z - e1a.z) + fabsf(h2a.z - e2a.z)) / 255.0f;
  ea.w = (fabsf(h0a.w - e0a.w) + fabsf(h1a.w - e1a.w) + fabsf(h2a.w - e2a.w)) / 255.0f;
  eb2.x = (fabsf(h0b.x - e0b.x) + fabsf(h1b.x - e1b.x) + fabsf(h2b.x - e2b.x)) / 255.0f;
  eb2.y = (fabsf(h0b.y - e0b.y) + fabsf(h1b.y - e1b.y) + fabsf(h2b.y - e2b.y)) / 255.0f;
  eb2.z = (fabsf(h0b.z - e0b.z) + fabsf(h1b.z - e1b.z) + fabsf(h2b.z - e2b.z)) / 255.0f;
  eb2.w = (fabsf(h0b.w - e0b.w) + fabsf(h1b.w - e1b.w) + fabsf(h2b.w - e2b.w)) / 255.0f;

  // sign-encode mask: m = (r >= e) ? r : -r   (r==0 case contributes 0 anyway)
  float4 ma, mb;
  ma.x = (ra.x >= ea.x) ? ra.x : -ra.x;
  ma.y = (ra.y >= ea.y) ? ra.y : -ra.y;
  ma.z = (ra.z >= ea.z) ? ra.z : -ra.z;
  ma.w = (ra.w >= ea.w) ? ra.w : -ra.w;
  mb.x = (rb.x >= eb2.x) ? rb.x : -rb.x;
  mb.y = (rb.y >= eb2.y) ? rb.y : -rb.y;
  mb.z = (rb.z >= eb2.z) ? rb.z : -rb.z;
  mb.w = (rb.w >= eb2.w) ? rb.w : -rb.w;

  float* __restrict__ rf = rfield + (((size_t)b << 18) + ((size_t)rem << 2));
  *(float4*)(rf) = ma;
  *(float4*)(rf + 4) = mb;

  float v1 = ra.x + ra.y + ra.z + ra.w + rb.x + rb.y + rb.z + rb.w;
  float v2 = ra.x * ra.x + ra.y * ra.y + ra.z * ra.z + ra.w * ra.w +
             rb.x * rb.x + rb.y * rb.y + rb.z * rb.z + rb.w * rb.w;

#pragma unroll
  for (int off = 32; off > 0; off >>= 1) {
    v1 += __shfl_down(v1, off, 64);
    v2 += __shfl_down(v2, off, 64);
  }
  __shared__ float red[2][4];
  const int wv = tid >> 6;
  if ((tid & 63) == 0) {
    red[0][wv] = v1;
    red[1][wv] = v2;
  }
  __syncthreads();
  if (tid == 0) {
    p_sum[bid] = red[0][0] + red[0][1] + red[0][2] + red[0][3];
    p_sum2[bid] = red[1][0] + red[1][1] + red[1][2] + red[1][3];
  }
}

// K2: 3x3 unbiased local var over |m|, masked by sign(m), on 8x256 tiles.
__global__ __launch_bounds__(256) void wl1_var(
    const float* __restrict__ rfield, float* __restrict__ p_loss) {
  __shared__ float rt[10][LDS_STRIDE];
  const int bid = blockIdx.x;
  const int b = bid >> 7;
  const int t = bid & 127;
  const int h0 = (t >> 1) << 3;  // 0,8,...,504
  const int w0 = (t & 1) << 8;   // 0 or 256
  const int tid = threadIdx.x;
  const int c4 = tid & 63;
  const int rs = tid >> 6;  // wave id -> uniform branches
  const float* __restrict__ rb = rfield + ((size_t)b << 18);

  // Stage A: halo rows 0..9 -> LDS (raw, sign preserved)
#pragma unroll
  for (int it = 0; it < 3; ++it) {
    int row = it * 4 + rs;
    if (row < 10) {
      int gh = reflect_h(h0 - 1 + row);
      float4 v = *(const float4*)(rb + gh * WW + w0 + 4 * c4);
      *(float4*)&rt[row][4 + 4 * c4] = v;
    }
  }
  // halo columns (20 scalar items)
  if (tid < 20) {
    int row = tid >> 1, side = tid & 1;
    int gh = reflect_h(h0 - 1 + row);
    int gw = side ? w0 + 256 : w0 - 1;
    if (gw < 0) gw = 1;
    if (gw > 511) gw = 1022 - gw;
    rt[row][side ? 260 : 3] = rb[gh * WW + gw];
  }
  __syncthreads();

  // Stage B: 2 rows x 4 cols per thread, pure LDS+VALU
  float v3 = 0.f;
#pragma unroll
  for (int rr = 0; rr < 2; ++rr) {
    const int o = rr * 4 + rs;  // output row, LDS center row = o+1
    float cs[6] = {0, 0, 0, 0, 0, 0}, cq[6] = {0, 0, 0, 0, 0, 0};
    float craw[4];
#pragma unroll
    for (int dr = 0; dr < 3; ++dr) {
      const float* lp = &rt[o + dr][4 * c4];
      float4 a = *(const float4*)(lp);
      float4 bq = *(const float4*)(lp + 4);
      float4 cq4 = *(const float4*)(lp + 8);
      float f3 = fabsf(a.w), f4 = fabsf(bq.x), f5 = fabsf(bq.y),
            f6 = fabsf(bq.z), f7 = fabsf(bq.w), f8 = fabsf(cq4.x);
      cs[0] += f3; cq[0] += f3 * f3;
      cs[1] += f4; cq[1] += f4 * f4;
      cs[2] += f5; cq[2] += f5 * f5;
      cs[3] += f6; cq[3] += f6 * f6;
      cs[4] += f7; cq[4] += f7 * f7;
      cs[5] += f8; cq[5] += f8 * f8;
      if (dr == 1) { craw[0] = bq.x; craw[1] = bq.y; craw[2] = bq.z; craw[3] = bq.w; }
    }
#pragma unroll
    for (int cc = 0; cc < 4; ++cc) {
      float s = cs[cc] + cs[cc + 1] + cs[cc + 2];
      float q = cq[cc] + cq[cc + 1] + cq[cc + 2];
      float pvar = (q - s * s / 9.0f) / 8.0f;
      float raw = craw[cc];
      float rc = fabsf(raw);
      if (raw >= 0.0f) v3 += pvar * (255.0f * rc);
    }
  }

#pragma unroll
  for (int off = 32; off > 0; off >>= 1) v3 += __shfl_down(v3, off, 64);
  __shared__ float red[4];
  if (c4 == 0) red[rs] = v3;
  __syncthreads();
  if (tid == 0) p_loss[bid] = red[0] + red[1] + red[2] + red[3];
}

// K3: final reduce — wave b handles batch b (128 partials each, 2/lane).
__global__ __launch_bounds__(1024) void wl1_final(
    const float* __restrict__ p_sum, const float* __restrict__ p_sum2,
    const float* __restrict__ p_loss, float* __restrict__ out) {
  const int tid = threadIdx.x;
  const int b = tid >> 6, k = tid & 63;
  const int i = b * 128 + k;
  double s = (double)p_sum[i] + (double)p_sum[i + 64];
  double s2 = (double)p_sum2[i] + (double)p_sum2[i + 64];
  double sl = (double)p_loss[i] + (double)p_loss[i + 64];
#pragma unroll
  for (int off = 32; off > 0; off >>= 1) {
    s += __shfl_down(s, off, 64);
    s2 += __shfl_down(s2, off, 64);
    sl += __shfl_down(sl, off, 64);
  }
  __shared__ double acc[BB];
  if (k == 0) {
    const double n = (double)HW;
    double var = (s2 - s * s / n) / (n - 1.0);
    acc[b] = pow(var, 0.2) * sl;
  }
  __syncthreads();
  if (tid == 0) {
    double tot = 0.0;
#pragma unroll
    for (int j = 0; j < BB; ++j) tot += acc[j];
    out[0] = (float)(tot / (double)((size_t)BB * CHW));
  }
}

extern "C" void kernel_launch(void* const* d_in, const int* in_sizes, int n_in,
                              void* d_out, int out_size, void* d_ws,
                              size_t ws_size, hipStream_t stream) {
  const float* sr = (const float*)d_in[0];
  const float* srema = (const float*)d_in[1];
  const float* hr = (const float*)d_in[2];
  float* out = (float*)d_out;

  float* p_sum = (float*)d_ws;            // [2048]
  float* p_sum2 = p_sum + NB1;            // [2048]
  float* p_loss = p_sum2 + NB1;           // [2048]
  float* rfield = p_loss + NB2;           // [16*512*512] = 16 MB, 16B-aligned

  wl1_stream<<<NB1, 256, 0, stream>>>(sr, srema, hr, rfield, p_sum, p_sum2);
  wl1_var<<<NB2, 256, 0, stream>>>(rfield, p_loss);
  wl1_final<<<1, 1024, 0, stream>>>(p_sum, p_sum2, p_loss, out);
}

// Round 7
// 163.296 us; speedup vs baseline: 1.0048x; 1.0048x over previous
//
#include <hip/hip_runtime.h>
#include <math.h>

// WL1 loss over [B=16, C=3, H=512, W=512] fp32.
//   r = sum_c|hr-sr|/255 ; e = sum_c|hr-ema|/255
//   patch_w[b] = (unbiased var of r over sample)^0.2
//   pixel_w = unbiased 3x3 local var of r (reflect pad)
//   loss = mean(|w*sr - w*hr|) = (1/N) sum patch_w * pixel_w * mask * 255*r
//
// R8: grid-stride steady-state streaming. R7 proved even a copy-shaped
// one-shot kernel caps at 2.7 TB/s (VALUBusy 8%, ~4 wave-loads in flight/CU):
// one-shot waves can't pipeline. The 6.3 TB/s copy ubench is a grid-stride
// LOOP - iterations give the scheduler independent loads to overlap. So K1
// becomes 1024 blocks x 4 independent iterations/thread (9 nontemporal
// float4 loads each, accumulators only cross-iter dep). K2 (LDS stencil on
// the 9x-smaller sign-encoded m-field) and K3 unchanged in structure.

#define BB 16
#define HH 512
#define WW 512
#define HW (HH * WW)
#define CHW (3 * HW)

#define NB1 1024   // K1 blocks: 64 per batch; 4 iters/thread
#define NB2 2048   // K2 blocks: tile 8x256
#define LDS_STRIDE 264  // col 3 = left halo, 4..259 = centers, 260 = right halo

typedef float f4v __attribute__((ext_vector_type(4)));

__device__ __forceinline__ f4v ntl(const float* p) {
  return __builtin_nontemporal_load((const f4v*)p);
}
__device__ __forceinline__ f4v absv(f4v a) {
  f4v r;
  r.x = fabsf(a.x); r.y = fabsf(a.y); r.z = fabsf(a.z); r.w = fabsf(a.w);
  return r;
}

__device__ __forceinline__ int reflect_h(int gh) {
  gh = gh < 0 ? -gh : gh;
  return gh >= HH ? 2 * HH - 2 - gh : gh;
}

// K1: streaming pass. Block bid -> batch b = bid>>6, 64 blocks/batch.
// Thread handles 4 quads (16 px) at stride 16384 quads within the batch plane.
__global__ __launch_bounds__(256) void wl1_stream(
    const float* __restrict__ sr, const float* __restrict__ srema,
    const float* __restrict__ hr, float* __restrict__ rfield,
    float* __restrict__ p_sum, float* __restrict__ p_sum2) {
  const int tid = threadIdx.x;
  const int bid = blockIdx.x;
  const int b = bid >> 6;                 // batch
  const int tq0 = ((bid & 63) << 8) | tid;  // base quad in plane (0..16383)
  const float* __restrict__ hb = hr + (size_t)b * CHW;
  const float* __restrict__ sb = sr + (size_t)b * CHW;
  const float* __restrict__ mb = srema + (size_t)b * CHW;
  float* __restrict__ rfb = rfield + ((size_t)b << 18);

  float v1 = 0.f, v2 = 0.f;
#pragma unroll
  for (int it = 0; it < 4; ++it) {
    const int qi = tq0 + (it << 14);      // quad index in plane (0..65535)
    const size_t off = (size_t)qi << 2;
    const float* hp = hb + off;
    const float* sp = sb + off;
    const float* ep = mb + off;
    f4v h0 = ntl(hp), h1 = ntl(hp + HW), h2 = ntl(hp + 2 * HW);
    f4v s0 = ntl(sp), s1 = ntl(sp + HW), s2 = ntl(sp + 2 * HW);
    f4v e0 = ntl(ep), e1 = ntl(ep + HW), e2 = ntl(ep + 2 * HW);

    f4v r4 = (absv(h0 - s0) + absv(h1 - s1) + absv(h2 - s2)) * (1.0f / 255.0f);
    f4v e4 = (absv(h0 - e0) + absv(h1 - e1) + absv(h2 - e2)) * (1.0f / 255.0f);

    // sign-encode mask: m = (r >= e) ? r : -r  (r contributes 0 when r==0)
    f4v m4;
    m4.x = (r4.x >= e4.x) ? r4.x : -r4.x;
    m4.y = (r4.y >= e4.y) ? r4.y : -r4.y;
    m4.z = (r4.z >= e4.z) ? r4.z : -r4.z;
    m4.w = (r4.w >= e4.w) ? r4.w : -r4.w;
    *(f4v*)(rfb + off) = m4;  // cached store; K2 re-reads it

    v1 += r4.x + r4.y + r4.z + r4.w;
    v2 += r4.x * r4.x + r4.y * r4.y + r4.z * r4.z + r4.w * r4.w;
  }

#pragma unroll
  for (int off = 32; off > 0; off >>= 1) {
    v1 += __shfl_down(v1, off, 64);
    v2 += __shfl_down(v2, off, 64);
  }
  __shared__ float red[2][4];
  const int wv = tid >> 6;
  if ((tid & 63) == 0) {
    red[0][wv] = v1;
    red[1][wv] = v2;
  }
  __syncthreads();
  if (tid == 0) {
    p_sum[bid] = red[0][0] + red[0][1] + red[0][2] + red[0][3];
    p_sum2[bid] = red[1][0] + red[1][1] + red[1][2] + red[1][3];
  }
}

// K2: 3x3 unbiased local var over |m|, masked by sign(m), on 8x256 tiles.
__global__ __launch_bounds__(256) void wl1_var(
    const float* __restrict__ rfield, float* __restrict__ p_loss) {
  __shared__ float rt[10][LDS_STRIDE];
  const int bid = blockIdx.x;
  const int b = bid >> 7;
  const int t = bid & 127;
  const int h0 = (t >> 1) << 3;  // 0,8,...,504
  const int w0 = (t & 1) << 8;   // 0 or 256
  const int tid = threadIdx.x;
  const int c4 = tid & 63;
  const int rs = tid >> 6;  // wave id -> uniform branches
  const float* __restrict__ rb = rfield + ((size_t)b << 18);

  // Stage A: halo rows 0..9 -> LDS (raw, sign preserved)
#pragma unroll
  for (int it = 0; it < 3; ++it) {
    int row = it * 4 + rs;
    if (row < 10) {
      int gh = reflect_h(h0 - 1 + row);
      float4 v = *(const float4*)(rb + gh * WW + w0 + 4 * c4);
      *(float4*)&rt[row][4 + 4 * c4] = v;
    }
  }
  // halo columns (20 scalar items)
  if (tid < 20) {
    int row = tid >> 1, side = tid & 1;
    int gh = reflect_h(h0 - 1 + row);
    int gw = side ? w0 + 256 : w0 - 1;
    if (gw < 0) gw = 1;
    if (gw > 511) gw = 1022 - gw;
    rt[row][side ? 260 : 3] = rb[gh * WW + gw];
  }
  __syncthreads();

  // Stage B: 2 rows x 4 cols per thread, pure LDS+VALU
  float v3 = 0.f;
#pragma unroll
  for (int rr = 0; rr < 2; ++rr) {
    const int o = rr * 4 + rs;  // output row, LDS center row = o+1
    float cs[6] = {0, 0, 0, 0, 0, 0}, cq[6] = {0, 0, 0, 0, 0, 0};
    float craw[4];
#pragma unroll
    for (int dr = 0; dr < 3; ++dr) {
      const float* lp = &rt[o + dr][4 * c4];
      float4 a = *(const float4*)(lp);
      float4 bq = *(const float4*)(lp + 4);
      float4 cq4 = *(const float4*)(lp + 8);
      float f3 = fabsf(a.w), f4 = fabsf(bq.x), f5 = fabsf(bq.y),
            f6 = fabsf(bq.z), f7 = fabsf(bq.w), f8 = fabsf(cq4.x);
      cs[0] += f3; cq[0] += f3 * f3;
      cs[1] += f4; cq[1] += f4 * f4;
      cs[2] += f5; cq[2] += f5 * f5;
      cs[3] += f6; cq[3] += f6 * f6;
      cs[4] += f7; cq[4] += f7 * f7;
      cs[5] += f8; cq[5] += f8 * f8;
      if (dr == 1) { craw[0] = bq.x; craw[1] = bq.y; craw[2] = bq.z; craw[3] = bq.w; }
    }
#pragma unroll
    for (int cc = 0; cc < 4; ++cc) {
      float s = cs[cc] + cs[cc + 1] + cs[cc + 2];
      float q = cq[cc] + cq[cc + 1] + cq[cc + 2];
      float pvar = (q - s * s / 9.0f) / 8.0f;
      float raw = craw[cc];
      float rc = fabsf(raw);
      if (raw >= 0.0f) v3 += pvar * (255.0f * rc);
    }
  }

#pragma unroll
  for (int off = 32; off > 0; off >>= 1) v3 += __shfl_down(v3, off, 64);
  __shared__ float red[4];
  if (c4 == 0) red[rs] = v3;
  __syncthreads();
  if (tid == 0) p_loss[bid] = red[0] + red[1] + red[2] + red[3];
}

// K3: final reduce — wave b handles batch b: 64 sum/sum2 partials, 128 loss.
__global__ __launch_bounds__(1024) void wl1_final(
    const float* __restrict__ p_sum, const float* __restrict__ p_sum2,
    const float* __restrict__ p_loss, float* __restrict__ out) {
  const int tid = threadIdx.x;
  const int b = tid >> 6, k = tid & 63;
  double s = (double)p_sum[b * 64 + k];
  double s2 = (double)p_sum2[b * 64 + k];
  double sl = (double)p_loss[b * 128 + k] + (double)p_loss[b * 128 + 64 + k];
#pragma unroll
  for (int off = 32; off > 0; off >>= 1) {
    s += __shfl_down(s, off, 64);
    s2 += __shfl_down(s2, off, 64);
    sl += __shfl_down(sl, off, 64);
  }
  __shared__ double acc[BB];
  if (k == 0) {
    const double n = (double)HW;
    double var = (s2 - s * s / n) / (n - 1.0);
    acc[b] = pow(var, 0.2) * sl;
  }
  __syncthreads();
  if (tid == 0) {
    double tot = 0.0;
#pragma unroll
    for (int j = 0; j < BB; ++j) tot += acc[j];
    out[0] = (float)(tot / (double)((size_t)BB * CHW));
  }
}

extern "C" void kernel_launch(void* const* d_in, const int* in_sizes, int n_in,
                              void* d_out, int out_size, void* d_ws,
                              size_t ws_size, hipStream_t stream) {
  const float* sr = (const float*)d_in[0];
  const float* srema = (const float*)d_in[1];
  const float* hr = (const float*)d_in[2];
  float* out = (float*)d_out;

  float* p_sum = (float*)d_ws;       // [1024]
  float* p_sum2 = p_sum + NB1;       // [1024]
  float* p_loss = p_sum2 + NB1;      // [2048]
  float* rfield = p_loss + NB2;      // [16*512*512] = 16 MB, 16B-aligned

  wl1_stream<<<NB1, 256, 0, stream>>>(sr, srema, hr, rfield, p_sum, p_sum2);
  wl1_var<<<NB2, 256, 0, stream>>>(rfield, p_loss);
  wl1_final<<<1, 1024, 0, stream>>>(p_sum, p_sum2, p_loss, out);
}